// Round 11
// baseline (139.601 us; speedup 1.0000x reference)
//
#include <hip/hip_runtime.h>
#include <hip/hip_bf16.h>
#include <stdint.h>

#define KDIM    256
#define NWORDS  1564         // sign words per column (= gemm grid: 64-row stripes)
#define NW      1563         // crossing words (ceil(99999/64))

typedef float  f32x4  __attribute__((ext_vector_type(4)));
typedef __bf16 bf16x8 __attribute__((ext_vector_type(8)));

// ---------- K0: build W, tile-major (B is read direct-to-reg) ----------
// Wt[t][j][32 bf16]: K-tile t (32 elems), row j. A (t,j) slice is 64B.
__global__ void build_w(const float* __restrict__ theta,
                        const float* __restrict__ noise,
                        __bf16* __restrict__ Wt) {
    int idx = blockIdx.x * 256 + threadIdx.x;   // 0..262143
    int j = idx >> 9;
    int d = idx & 511;
    float v;
    if (j < KDIM) v = theta[j * 512 + d];
    else          v = theta[(j - KDIM) * 512 + d] + 0.01f * noise[(j - KDIM) * 512 + d];
    Wt[((d >> 5) * 512 + j) * 32 + (d & 31)] = (__bf16)v;
}

// ---------- K1: super-step MFMA GEMM -> packed sign bits ----------
// Tile 64(M) x 512(N), 512 threads = 8 waves (wave = 64x64 col panel).
// SUPER-STEP BK=128 (4 K-tiles): A staged once per super-step into a
// double-buffered 2x16KB LDS (per thread: 4 float4 -> cvt -> 2 swizzled
// ds_write_b128), ONE barrier per super-step (4 per block, vs 16-32 before)
// -- waves free-run across 4 K-tiles, so correlated load-latency stalls no
// longer convoy at a per-tile barrier. B: direct global->reg from L2-resident
// tile-major Wt, depth-2 (R10-proven). All waits compiler-counted.
__global__ void __launch_bounds__(512, 2)
gemm_signs(const float* __restrict__ basis,
           const __bf16* __restrict__ Wt,
           uint64_t* __restrict__ sbits) {
    __shared__ char smem[34816];   // K-loop: A dbuf 2x16KB; epilogue [512][68]

    const int tid    = threadIdx.x;
    const int lane   = tid & 63;
    const int wc     = tid >> 6;       // wave 0..7 = column panel
    const int lane16 = lane & 15;
    const int lgrp   = lane >> 4;

    // bijective XCD swizzle: nwg=1564=8*195+4 (m204)
    const int orig = blockIdx.x;
    const int x    = orig & 7;
    const int bm   = (x < 4 ? x * 196 : 784 + (x - 4) * 195) + (orig >> 3);  // 0..1563

    // ---- A staging geometry: thread -> (row rl, 16-f32 slice oct) ----
    const int rl  = tid >> 3;          // local row 0..63
    const int oct = tid & 7;           // 16 f32 (-> 2 bf16 granules) per thread
    int r = bm * 64 + rl; if (r > 99999) r = 99999;   // tail clamp (masked later)
    const float* ag = basis + (size_t)r * 512 + oct * 16;
    const int gsz = rl & 15;           // granule-XOR involution key

    // ---- B fragment addressing (direct global, tile-major) ----
    const char* wbase = (const char*)Wt;
    int bfofs[4];
    #pragma unroll
    for (int n = 0; n < 4; ++n)
        bfofs[n] = (wc * 64 + n * 16 + lane16) * 64 + lgrp * 16;

    f32x4  acc[4][4] = {};
    float4 ra[4];                      // A(s+1) staging regs
    bf16x8 bfr[2][4];                  // B(t) frags, depth 2

    auto write_A = [&](int q) {        // cvt ra -> 2 swizzled b128 into buffer q
        char* wb = smem + (q << 14);
        #pragma unroll
        for (int u = 0; u < 2; ++u) {
            bf16x8 w;
            w[0] = (__bf16)ra[2*u].x;   w[1] = (__bf16)ra[2*u].y;
            w[2] = (__bf16)ra[2*u].z;   w[3] = (__bf16)ra[2*u].w;
            w[4] = (__bf16)ra[2*u+1].x; w[5] = (__bf16)ra[2*u+1].y;
            w[6] = (__bf16)ra[2*u+1].z; w[7] = (__bf16)ra[2*u+1].w;
            *(bf16x8*)(wb + rl * 256 + (((2*oct + u) ^ gsz) << 4)) = w;
        }
    };

    // ---- prologue: A(0)->buf0, B(0) frags, A(1) issued, one barrier ----
    #pragma unroll
    for (int u = 0; u < 4; ++u) ra[u] = *(const float4*)(ag + u * 4);
    #pragma unroll
    for (int n = 0; n < 4; ++n) bfr[0][n] = *(const bf16x8*)(wbase + bfofs[n]);
    write_A(0);                        // compiler waits ra's vmcnt here
    #pragma unroll
    for (int u = 0; u < 4; ++u) ra[u] = *(const float4*)(ag + 128 + u * 4);
    asm volatile("s_waitcnt lgkmcnt(0)" ::: "memory");
    __builtin_amdgcn_s_barrier();

    #pragma unroll
    for (int s = 0; s < 4; ++s) {
        const char* ab = smem + ((s & 1) << 14);
        #pragma unroll
        for (int ti = 0; ti < 4; ++ti) {
            const int t = s * 4 + ti;
            if (t < 15) {              // B(t+1) frags, depth-2 regs
                #pragma unroll
                for (int n = 0; n < 4; ++n)
                    bfr[(t + 1) & 1][n] =
                        *(const bf16x8*)(wbase + (size_t)(t + 1) * 32768 + bfofs[n]);
            }
            bf16x8 af[4];
            #pragma unroll
            for (int m = 0; m < 4; ++m) {
                int rr = m * 16 + lane16;
                af[m] = *(const bf16x8*)(ab + rr * 256
                           + (((ti * 4 + lgrp) ^ (rr & 15)) << 4));
            }
            __builtin_amdgcn_sched_barrier(0);
            __builtin_amdgcn_s_setprio(1);
            #pragma unroll
            for (int m = 0; m < 4; ++m)
                #pragma unroll
                for (int n = 0; n < 4; ++n)
                    acc[m][n] = __builtin_amdgcn_mfma_f32_16x16x32_bf16(
                        af[m], bfr[t & 1][n], acc[m][n], 0, 0, 0);
            __builtin_amdgcn_s_setprio(0);
        }
        if (s < 3) {
            write_A((s + 1) & 1);      // compiler waits A(s+1) vmcnt here
            if (s < 2) {
                #pragma unroll
                for (int u = 0; u < 4; ++u)
                    ra[u] = *(const float4*)(ag + (s + 2) * 128 + u * 4);
            }
            asm volatile("s_waitcnt lgkmcnt(0)" ::: "memory");
            __builtin_amdgcn_s_barrier();    // ONE barrier per super-step
        }
    }

    // ---- epilogue: sign bytes -> LDS transpose -> multiply-pack -> u64 ----
    // C/D layout: col = lane&15, row = (lane>>4)*4 + reg
    __builtin_amdgcn_s_barrier();                 // done with K-loop LDS
    unsigned char* sb = (unsigned char*)smem;     // [512 cols][68B] = 34.8KB
    #pragma unroll
    for (int m = 0; m < 4; ++m) {
        #pragma unroll
        for (int n = 0; n < 4; ++n) {
            int cc = wc * 64 + n * 16 + lane16;   // col 0..511
            int rb = m * 16 + lgrp * 4;           // row base 0..60
            uint32_t pk = 0;
            #pragma unroll
            for (int rg = 0; rg < 4; ++rg)
                pk |= (acc[m][n][rg] < 0.0f ? 1u : 0u) << (8 * rg);
            *(uint32_t*)&sb[cc * 68 + rb] = pk;
        }
    }
    asm volatile("s_waitcnt lgkmcnt(0)" ::: "memory");
    __builtin_amdgcn_s_barrier();

    {   // one thread per column; 64 sign bytes -> u64; word index = bm
        const unsigned char* src = &sb[tid * 68];
        uint64_t wbits = 0;
        #pragma unroll
        for (int k = 0; k < 16; ++k) {
            uint32_t qv = *(const uint32_t*)&src[4 * k];
            uint32_t p4 = ((qv & 0x01010101u) * 0x10204080u) >> 28;
            wbits |= (uint64_t)p4 << (4 * k);
        }
        sbits[(size_t)bm * 512 + tid] = wbits;    // 4KB contiguous per block
    }
}

// ---------- K2: crossing masks from sign bits ----------
__global__ void crossing_masks(const uint64_t* __restrict__ sbits,
                               uint64_t* __restrict__ maskT) {
    const int w = blockIdx.x;       // 0..1562
    const int j = threadIdx.x;      // 0..255
    uint64_t s0r = sbits[(size_t)w * 512 + j];
    uint64_t s0p = sbits[(size_t)w * 512 + 256 + j];
    uint64_t s1r = sbits[(size_t)(w + 1) * 512 + j];
    uint64_t s1p = sbits[(size_t)(w + 1) * 512 + 256 + j];
    uint64_t cr = s0r ^ ((s0r >> 1) | (s1r << 63));
    uint64_t cp = s0p ^ ((s0p >> 1) | (s1p << 63));
    uint64_t m = cr & cp;
    if (w == NW - 1) m &= 0x7FFFFFFFull;    // 31 valid crossings in last word
    maskT[(size_t)w * 256 + j] = m;
}

// ---------- K3: pairwise AND-popcount ----------
__global__ void zero_out(float* __restrict__ out) {
    int i = blockIdx.x * 256 + threadIdx.x;
    if (i < 32640) out[i] = 0.0f;
}

__global__ void pair_popcount(const uint64_t* __restrict__ maskT,
                              float* __restrict__ out) {
    const int i = blockIdx.x;   // 0..255
    const int c = blockIdx.y;   // 0..7 word chunk
    const int j = threadIdx.x;  // 0..255
    if (j <= i) return;
    int w0 = c * 196;
    int w1 = w0 + 196; if (w1 > NW) w1 = NW;
    uint32_t sum = 0;
    #pragma unroll 4
    for (int w = w0; w < w1; ++w) {
        uint64_t mi = maskT[(size_t)w * 256 + i];   // block-uniform -> scalar
        uint64_t mj = maskT[(size_t)w * 256 + j];   // coalesced
        sum += (uint32_t)__popcll(mi & mj);
    }
    const size_t idx = (size_t)i * (2 * KDIM - i - 1) / 2 + (size_t)(j - i - 1);
    atomicAdd(&out[idx], (float)sum);   // exact-integer f32 adds -> deterministic
}

extern "C" void kernel_launch(void* const* d_in, const int* in_sizes, int n_in,
                              void* d_out, int out_size, void* d_ws, size_t ws_size,
                              hipStream_t stream) {
    const float* theta = (const float*)d_in[0];
    const float* basis = (const float*)d_in[1];
    const float* noise = (const float*)d_in[2];
    float* out = (float*)d_out;

    char* ws = (char*)d_ws;
    __bf16*   Wt    = (__bf16*)ws;                              // 512 KB, tile-major
    uint64_t* sbits = (uint64_t*)(ws + 524288);                 // 1564*512*8 = 6.41 MB
    uint64_t* maskT = (uint64_t*)(ws + 524288 + (size_t)NWORDS * 512 * 8); // 3.2 MB

    hipLaunchKernelGGL(build_w,        dim3(1024),    dim3(256), 0, stream, theta, noise, Wt);
    hipLaunchKernelGGL(gemm_signs,     dim3(NWORDS),  dim3(512), 0, stream, basis, Wt, sbits);
    hipLaunchKernelGGL(crossing_masks, dim3(NW),      dim3(256), 0, stream, sbits, maskT);
    hipLaunchKernelGGL(zero_out,       dim3(128),     dim3(256), 0, stream, out);
    hipLaunchKernelGGL(pair_popcount,  dim3(KDIM, 8), dim3(256), 0, stream, maskT, out);
}